// Round 3
// baseline (4464.640 us; speedup 1.0000x reference)
//
#include <hip/hip_runtime.h>
#include <math.h>

// Problem constants
#define BB   64
#define LL   720
#define CC   512
#define FF   361
#define KTOP 20
#define NCAND 32
#define NW   768    // padded twiddle cols: 2*361=722 -> 768
#define NMAG 384    // NW/2

// ---------------------------------------------------------------------------
// Generic batched tile transpose: in (z, R, Cc) -> out (z, Cc, R)
// ---------------------------------------------------------------------------
__global__ __launch_bounds__(256) void transpose_kernel(
    const float* __restrict__ in, float* __restrict__ out,
    int R, int Cc, long sIn, long sOut) {
  __shared__ float tile[32][33];
  const float* inp = in + (long)blockIdx.z * sIn;
  float* outp = out + (long)blockIdx.z * sOut;
  int r0 = blockIdx.y * 32, c0 = blockIdx.x * 32;
  int tx = threadIdx.x, ty = threadIdx.y;
#pragma unroll
  for (int i = 0; i < 4; ++i) {
    int r = r0 + ty + 8 * i, c = c0 + tx;
    if (r < R && c < Cc) tile[ty + 8 * i][tx] = inp[(long)r * Cc + c];
  }
  __syncthreads();
#pragma unroll
  for (int i = 0; i < 4; ++i) {
    int c = c0 + ty + 8 * i, r = r0 + tx;
    if (c < Cc && r < R) outp[(long)c * R + r] = tile[tx][ty + 8 * i];
  }
}

// ---------------------------------------------------------------------------
// residual[b,l,c] = x[b,l,c] - xfilt[b,c,l]
// ---------------------------------------------------------------------------
__global__ __launch_bounds__(256) void residual_kernel(
    const float* __restrict__ x, const float* __restrict__ xf,
    float* __restrict__ out) {
  __shared__ float tile[32][33];
  int b = blockIdx.z;
  const float* xfp = xf + (long)b * CC * LL;
  int c0 = blockIdx.x * 32, l0 = blockIdx.y * 32;
  int tx = threadIdx.x, ty = threadIdx.y;
#pragma unroll
  for (int i = 0; i < 4; ++i) {
    int c = c0 + ty + 8 * i, l = l0 + tx;
    if (l < LL) tile[ty + 8 * i][tx] = xfp[(long)c * LL + l];
  }
  __syncthreads();
  long xbase = (long)b * LL * CC;
#pragma unroll
  for (int i = 0; i < 4; ++i) {
    int l = l0 + ty + 8 * i, c = c0 + tx;
    if (l < LL) {
      long off = xbase + (long)l * CC + c;
      out[off] = x[off] - tile[tx][ty + 8 * i];
    }
  }
}

// ---------------------------------------------------------------------------
// One-time table fill: WDFT [720 x 768] fp32 (col 2f=cos, 2f+1=-sin, pad 0)
// and CT64 [1260] fp64 (ct[j]=cos(2pi*(j mod 720)/720); sin(k)=ct[k+540]).
// ---------------------------------------------------------------------------
__global__ __launch_bounds__(256) void fill_tables_kernel(
    float* __restrict__ wdft, double* __restrict__ ct64) {
  const double W0d = 8.7266462599716478846e-3;  // 2*pi/720
  int gid = blockIdx.x * 256 + threadIdx.x;
  if (gid < 720 * NW) {
    int t = gid / NW, c = gid % NW;
    float v = 0.f;
    if (c < 2 * FF) {
      int f = c >> 1;
      int k = (int)(((long)f * t) % 720);
      double ang = (double)k * W0d;
      v = (c & 1) ? (float)(-sin(ang)) : (float)cos(ang);
    }
    wdft[gid] = v;
  } else if (gid < 720 * NW + 1260) {
    int j = gid - 720 * NW;
    int j2 = (j >= 720) ? j - 720 : j;
    ct64[j] = cos((double)j2 * W0d);
  }
}

// ---------------------------------------------------------------------------
// fp32 tiled GEMM: Cout = epilogue(A[M,K] @ W[K,N]).
// BM=BN=64, BK=16, 256 threads, 4x4 acc per thread.
// EPI: 0 = store (acc+bias)
//      1 = store relu(acc+bias)
//      2 = store relu(acc+bias+Cin)
//      3 = store Cin + relu(acc+bias)
//      4 = magnitude epilogue: cols are (re,im) interleaved; store
//          re^2+im^2 into Cout[M x N/2]
// BIASM: 0 none, 1 per-column, 2 per-row
// ---------------------------------------------------------------------------
template <int EPI, int BIASM>
__global__ __launch_bounds__(256) void gemm_f32(
    const float* __restrict__ A, const float* __restrict__ W,
    const float* __restrict__ bias, const float* __restrict__ Cin,
    float* __restrict__ Cout, int M, int N, int K,
    long sA, long sW, long sC) {
  __shared__ float As[16][68];
  __shared__ float Ws[16][68];
  A += (long)blockIdx.z * sA;
  W += (long)blockIdx.z * sW;
  Cin += (long)blockIdx.z * sC;
  Cout += (long)blockIdx.z * sC;
  const int m0 = blockIdx.y * 64, n0 = blockIdx.x * 64;
  const int tid = threadIdx.x;
  const int tx = tid & 15, ty = tid >> 4;
  const int arow = tid >> 2, ac = (tid & 3) * 4;
  const int wrow = tid >> 4, wc = (tid & 15) * 4;

  float acc[4][4] = {};
  for (int k0 = 0; k0 < K; k0 += 16) {
    float4 av;
    int gr = m0 + arow;
    if (gr < M) av = *(const float4*)&A[(long)gr * K + k0 + ac];
    else        av = make_float4(0.f, 0.f, 0.f, 0.f);
    float4 wv = *(const float4*)&W[(long)(k0 + wrow) * N + n0 + wc];
    __syncthreads();
    As[ac + 0][arow] = av.x; As[ac + 1][arow] = av.y;
    As[ac + 2][arow] = av.z; As[ac + 3][arow] = av.w;
    *(float4*)&Ws[wrow][wc] = wv;
    __syncthreads();
#pragma unroll
    for (int kk = 0; kk < 16; ++kk) {
      float4 a = *(const float4*)&As[kk][ty * 4];
      float4 b = *(const float4*)&Ws[kk][tx * 4];
      float aa[4] = {a.x, a.y, a.z, a.w};
      float bb[4] = {b.x, b.y, b.z, b.w};
#pragma unroll
      for (int i = 0; i < 4; ++i)
#pragma unroll
        for (int j = 0; j < 4; ++j)
          acc[i][j] = fmaf(aa[i], bb[j], acc[i][j]);
    }
  }

  if (EPI == 4) {
#pragma unroll
    for (int i = 0; i < 4; ++i) {
      int r = m0 + ty * 4 + i;
      if (r >= M) continue;
      long off = (long)r * (N >> 1) + (n0 >> 1) + tx * 2;
      Cout[off + 0] = acc[i][0] * acc[i][0] + acc[i][1] * acc[i][1];
      Cout[off + 1] = acc[i][2] * acc[i][2] + acc[i][3] * acc[i][3];
    }
    return;
  }

#pragma unroll
  for (int i = 0; i < 4; ++i) {
    int r = m0 + ty * 4 + i;
    if (r >= M) continue;
    float rb = (BIASM == 2) ? bias[r] : 0.f;
#pragma unroll
    for (int j = 0; j < 4; ++j) {
      int cix = n0 + tx * 4 + j;
      float v = acc[i][j];
      if (BIASM == 1) v += bias[cix];
      if (BIASM == 2) v += rb;
      long off = (long)r * N + cix;
      if (EPI == 0) Cout[off] = v;
      else if (EPI == 1) Cout[off] = fmaxf(v, 0.f);
      else if (EPI == 2) Cout[off] = fmaxf(v + Cin[off], 0.f);
      else Cout[off] = Cin[off] + fmaxf(v, 0.f);
    }
  }
}

// ---------------------------------------------------------------------------
// Per-series: top-32 candidates from fp32 mags, fp64 refinement of those 32
// (exact table), fp64 top-20 rank (ties -> lower freq index, matching
// lax.top_k), fp64 reconstruction. One block per series row.
// ---------------------------------------------------------------------------
__global__ __launch_bounds__(256) void refine_topk_kernel(
    const float* __restrict__ smag_g, const float* __restrict__ xt,
    const double* __restrict__ ct64, float* __restrict__ xfilt) {
  __shared__ float  sx[720];
  __shared__ float  se[361];
  __shared__ float  so[361];
  __shared__ double ct[1260];
  __shared__ float  smag[NMAG];
  __shared__ int    cand[NCAND];
  __shared__ double cre[NCAND], cim[NCAND], cmag[NCAND];
  __shared__ int    self_[KTOP];
  __shared__ double selre[KTOP], selim[KTOP];
  __shared__ float  swv[4];
  __shared__ int    swi[4];

  const int tid = threadIdx.x;
  const long r = blockIdx.x;
  const long base = r * LL;

  for (int t = tid; t < LL; t += 256) sx[t] = xt[base + t];
  for (int j = tid; j < 1260; j += 256) ct[j] = ct64[j];
  {
    float v = smag_g[r * NMAG + tid];
    smag[tid] = (tid < FF) ? v : -1.f;
    if (tid < NMAG - 256) {
      float v2 = smag_g[r * NMAG + 256 + tid];
      smag[256 + tid] = (256 + tid < FF) ? v2 : -1.f;
    }
  }
  __syncthreads();
  for (int t = tid; t < FF; t += 256) {
    if (t == 0)        { se[0] = sx[0];     so[0] = 0.f; }
    else if (t == 360) { se[360] = sx[360]; so[360] = 0.f; }
    else               { se[t] = sx[t] + sx[720 - t]; so[t] = sx[t] - sx[720 - t]; }
  }
  __syncthreads();

  // top-32 candidates by fp32 magnitude (repeated block argmax)
  for (int it = 0; it < NCAND; ++it) {
    float v = smag[tid]; int bi = tid;
    if (tid < NMAG - 256) {
      float v2 = smag[256 + tid];
      if (v2 > v) { v = v2; bi = 256 + tid; }   // higher index loses ties
    }
#pragma unroll
    for (int off = 32; off > 0; off >>= 1) {
      float ov = __shfl_down(v, off);
      int oi = __shfl_down(bi, off);
      if (ov > v || (ov == v && oi < bi)) { v = ov; bi = oi; }
    }
    if ((tid & 63) == 0) { swv[tid >> 6] = v; swi[tid >> 6] = bi; }
    __syncthreads();
    if (tid == 0) {
      float bv = swv[0]; int bb = swi[0];
      for (int w = 1; w < 4; ++w)
        if (swv[w] > bv || (swv[w] == bv && swi[w] < bb)) { bv = swv[w]; bb = swi[w]; }
      cand[it] = bb;
      smag[bb] = -2.f;
    }
    __syncthreads();
  }

  // fp64 refinement of the 32 candidates (exact table twiddles)
  if (tid < NCAND) {
    int f = cand[tid];
    double re = (double)se[0], im = 0.0;
    int k = 0;
    for (int t = 1; t < 360; ++t) {
      k += f; if (k >= 720) k -= 720;
      re += (double)se[t] * ct[k];
      im -= (double)so[t] * ct[k + 540];
    }
    re += (f & 1) ? -(double)se[360] : (double)se[360];
    cre[tid] = re; cim[tid] = im; cmag[tid] = re * re + im * im;
  }
  __syncthreads();

  // fp64 top-20 among candidates (ties -> lower freq index)
  if (tid == 0) {
    unsigned used = 0u;
    for (int it = 0; it < KTOP; ++it) {
      double bv = -1.0; int bj = 0, bf = 1 << 30;
      for (int j = 0; j < NCAND; ++j) {
        if (used & (1u << j)) continue;
        if (cmag[j] > bv || (cmag[j] == bv && cand[j] < bf)) {
          bv = cmag[j]; bj = j; bf = cand[j];
        }
      }
      used |= 1u << bj;
      self_[it] = cand[bj]; selre[it] = cre[bj]; selim[it] = cim[bj];
    }
  }
  __syncthreads();

  // fp64 reconstruction
  const double invL = 1.0 / 720.0;
  for (int t = tid; t < LL; t += 256) {
    double acc = 0.0;
#pragma unroll
    for (int it = 0; it < KTOP; ++it) {
      int f = self_[it];
      int k = (f * t) % 720;
      double w = (f == 0 || f == 360) ? 1.0 : 2.0;
      acc += w * (selre[it] * ct[k] - selim[it] * ct[k + 540]);
    }
    xfilt[base + t] = (float)(acc * invL);
  }
}

// ---------------------------------------------------------------------------
extern "C" void kernel_launch(void* const* d_in, const int* in_sizes, int n_in,
                              void* d_out, int out_size, void* d_ws, size_t ws_size,
                              hipStream_t stream) {
  const float* x      = (const float*)d_in[0];
  const float* w_freq = (const float*)d_in[1];
  const float* b_freq = (const float*)d_in[2];
  const float* w_all1 = (const float*)d_in[3];
  const float* b_all1 = (const float*)d_in[4];
  const float* w_all2 = (const float*)d_in[5];
  const float* b_all2 = (const float*)d_in[6];
  const float* w_time = (const float*)d_in[7];
  const float* b_time = (const float*)d_in[8];
  const float* w_chan = (const float*)d_in[9];
  const float* b_chan = (const float*)d_in[10];
  const float* w_proj = (const float*)d_in[11];
  const float* b_proj = (const float*)d_in[12];

  float* out0 = (float*)d_out;                       // residual (64,720,512)
  float* out1 = out0 + (size_t)BB * LL * CC;         // pred     (64,720,512)

  // workspace layout (floats). Peak = 53,661,696 floats = 214.6 MB
  // (same footprint as the round-2 passing kernel).
  float* ws  = (float*)d_ws;
  float* XT  = ws;                    // (64,512,720)  23,592,960
  float* XF  = XT + 23592960;         // (64,512,720)  23,592,960
  float* R2  = XF + 23592960;         // scratch region: 6,475,776 floats
  // Phase A (DFT) usage of R2:
  double* CT64 = (double*)R2;         // 1260 doubles = 2520 floats
  float* WDFT  = R2 + 2520;           // (720,768)    552,960
  float* SMAG  = R2 + 555480;         // (8192,384) 3,145,728 (per chunk)
  // Phase B (MLP/mixer) usage of R2 (after DFT done):
  float* H   = R2;                    // (32768,64)     2,097,152
  float* A1  = R2 + 2097152;          // (32768,128)    4,194,304
  float* WPT = R2 + 6291456;          // (720,256)        184,320
  // Reuse of big regions in phase B:
  float* Z   = XF;                    // (32768,256) (XF consumed by stage 5)
  float* T   = XF + 8388608;          // (32768,256)
  float* TT  = XT;                    // (64,256,512) (XT consumed by stage 7)
  float* CO  = XT + 8388608;          // (64,256,512)

  dim3 tb(32, 8);

  // 1) x (b,720,512) -> XT (b,512,720)
  transpose_kernel<<<dim3(16, 23, BB), tb, 0, stream>>>(
      x, XT, LL, CC, (long)LL * CC, (long)LL * CC);
  // 2) twiddle tables (fp32 GEMM matrix + fp64 exact table)
  fill_tables_kernel<<<(720 * NW + 1260 + 255) / 256, 256, 0, stream>>>(
      WDFT, CT64);
  // 3) DFT (as fp32 GEMM with |X|^2 epilogue) + fp64 refine, 4 row-chunks
  for (int q = 0; q < 4; ++q) {
    const float* xtq = XT + (long)q * 8192 * LL;
    float* xfq = XF + (long)q * 8192 * LL;
    gemm_f32<4, 0><<<dim3(NW / 64, 128, 1), 256, 0, stream>>>(
        xtq, WDFT, nullptr, nullptr, SMAG, 8192, NW, LL, 0, 0, 0);
    refine_topk_kernel<<<8192, 256, 0, stream>>>(SMAG, xtq, CT64, xfq);
  }
  // 4) w_proj (256,720) -> WPT (720,256)
  transpose_kernel<<<dim3(23, 8, 1), tb, 0, stream>>>(
      w_proj, WPT, 256, 720, 0, 0);
  // 5) residual = x - XF^T -> out0
  residual_kernel<<<dim3(16, 23, BB), tb, 0, stream>>>(x, XF, out0);
  // 6) h = relu(XF @ w_freq + b_freq)            (32768,720)x(720,64)
  gemm_f32<1, 1><<<dim3(1, 512, 1), 256, 0, stream>>>(
      XF, w_freq, b_freq, nullptr, H, 32768, 64, 720, 0, 0, 0);
  // 7) tmp = h @ w_all1[:64]                     (32768,64)x(64,128)
  gemm_f32<0, 0><<<dim3(2, 512, 1), 256, 0, stream>>>(
      H, w_all1, nullptr, nullptr, A1, 32768, 128, 64, 0, 0, 0);
  // 8) a1 = relu(tmp + XT @ w_all1[64:] + b_all1) (32768,720)x(720,128)
  gemm_f32<2, 1><<<dim3(2, 512, 1), 256, 0, stream>>>(
      XT, w_all1 + 64 * 128, b_all1, A1, A1, 32768, 128, 720, 0, 0, 0);
  // 9) z = a1 @ w_all2 + b_all2                  (32768,128)x(128,256)
  gemm_f32<0, 1><<<dim3(4, 512, 1), 256, 0, stream>>>(
      A1, w_all2, b_all2, nullptr, Z, 32768, 256, 128, 0, 0, 0);
  // 10) t = z + relu(z @ w_time + b_time)        (32768,256)x(256,256)
  gemm_f32<3, 1><<<dim3(4, 512, 1), 256, 0, stream>>>(
      Z, w_time, b_time, Z, T, 32768, 256, 256, 0, 0, 0);
  // 11) T (b,512,256) -> TT (b,256,512)
  transpose_kernel<<<dim3(8, 16, BB), tb, 0, stream>>>(
      T, TT, 512, 256, (long)512 * 256, (long)512 * 256);
  // 12) c = TT + relu(TT @ w_chan + b_chan)      (16384,512)x(512,512)
  gemm_f32<3, 1><<<dim3(8, 256, 1), 256, 0, stream>>>(
      TT, w_chan, b_chan, TT, CO, 16384, 512, 512, 0, 0, 0);
  // 13) pred[b,p,c] = WPT[p,:] @ CO[b,:,c] + b_proj[p]  (720,256)x(256,512) x64
  gemm_f32<0, 2><<<dim3(8, 12, BB), 256, 0, stream>>>(
      WPT, CO, b_proj, nullptr, out1, 720, 512, 256,
      0, (long)256 * 512, (long)LL * CC);
}